// Round 1
// baseline (496.917 us; speedup 1.0000x reference)
//
#include <hip/hip_runtime.h>

// GCN: out = A*(relu(A*(X*W1)+b1)*W2)+b2, A sparse COO, sorted row[].
// N=100000, E=3200000, IN=256, HID=256, OUT=64.
// Pipeline (5 launches, prep fused into spmm, pipelined gemm K-loops):
//   setup: rowptr + W1T + W2T
//   gemm1: Q1,s1 = int8rowquant(bf16(X)@W1)   (512thr, BM=128 BN=256)
//   spmm1: H = relu(A@deq(Q1)+b1) -> bf16     (w = vals[e]*s1[col[e]] in-loop)
//   gemm2: Q2,s2 = int8rowquant(H@W2)         (256thr, BM=128 BN=64)
//   spmm2: out = A@deq(Q2)+b2 -> fp32

constexpr int IN_SIZE = 256;
constexpr int HID = 256;
constexpr int OUTF = 64;

typedef __bf16 bf16x8 __attribute__((ext_vector_type(8)));
typedef float f32x4 __attribute__((ext_vector_type(4)));

__device__ __forceinline__ ushort f2b(float f) {
    uint u = __float_as_uint(f);
    uint r = (u + 0x7fffu + ((u >> 16) & 1u)) >> 16;   // RNE
    return (ushort)r;
}

// ---------------------------------------------------------------------------
// setup: blocks [0,rpB): row_ptr; [rpB,rpB+256): W1T; [rpB+256,rpB+320): W2T
__global__ void setup_kernel(const int* __restrict__ row, int* __restrict__ rp,
                             const float* __restrict__ W1, ushort* __restrict__ W1T,
                             const float* __restrict__ W2, ushort* __restrict__ W2T,
                             int n, int E, int rpB) {
    int b = blockIdx.x;
    if (b < rpB) {
        int i = b * 256 + threadIdx.x;
        if (i > n) return;
        int lo = 0, hi = E;
        while (lo < hi) {
            int mid = (lo + hi) >> 1;
            if (row[mid] < i) lo = mid + 1; else hi = mid;
        }
        rp[i] = lo;
    } else if (b < rpB + 256) {
        int nn = b - rpB;
        int k = threadIdx.x;
        W1T[(size_t)nn * 256 + k] = f2b(W1[(size_t)k * 256 + nn]);
    } else {
        int nn = b - rpB - 256;
        int k = threadIdx.x;
        W2T[(size_t)nn * 256 + k] = f2b(W2[(size_t)k * 64 + nn]);
    }
}

// ---------------------------------------------------------------------------
// GEMM1+quant: Q[M,256] int8, s1[M] from bf16(X_f32[M,256]) @ Bt[256,256]^T.
// BM=128, BN=256 (full width, X read once), BK=32. 512 threads = 8 waves in
// 2x4; wave tile 64x64 -> acc[4][4]. K-loop software-pipelined: next tile's
// global loads issue after the LDS-publish barrier, hide under ds_read+MFMA.
__global__ __launch_bounds__(512)
void gemm1_q(const float* __restrict__ A, const ushort* __restrict__ Bt,
             char* __restrict__ Q, float* __restrict__ s1, int M) {
    constexpr int K = 256;
    __shared__ ushort As[128 * 40];
    __shared__ ushort Bs[256 * 40];
    __shared__ float red[4][128];
    __shared__ float fin[128];
    const int tid = threadIdx.x;
    const int wave = tid >> 6, lane = tid & 63;
    const int quad = lane >> 4, l = lane & 15;
    const int wr = wave >> 2, wc = wave & 3;     // 2 x 4 wave grid
    const int m0 = blockIdx.x * 128;

    const int ar = tid >> 2;
    const int ak = (tid & 3) * 8;
    const size_t aoff = (size_t)min(m0 + ar, M - 1) * K + ak;
    const int bn = tid >> 2;
    const int bkp = (tid & 3) * 8;
    const size_t boff0 = (size_t)bn * K + bkp;
    const size_t boff1 = (size_t)(bn + 128) * K + bkp;

    f32x4 acc[4][4] = {};

    // prologue: k0 = 0 tile
    float4 a0 = *(const float4*)(A + aoff);
    float4 a1 = *(const float4*)(A + aoff + 4);
    uint4 bv0 = *(const uint4*)(Bt + boff0);
    uint4 bv1 = *(const uint4*)(Bt + boff1);

    for (int k0 = 0; k0 < K; k0 += 32) {
        uint4 pa;
        pa.x = (uint)f2b(a0.x) | ((uint)f2b(a0.y) << 16);
        pa.y = (uint)f2b(a0.z) | ((uint)f2b(a0.w) << 16);
        pa.z = (uint)f2b(a1.x) | ((uint)f2b(a1.y) << 16);
        pa.w = (uint)f2b(a1.z) | ((uint)f2b(a1.w) << 16);
        __syncthreads();
        *(uint4*)&As[ar * 40 + ak] = pa;
        *(uint4*)&Bs[bn * 40 + bkp] = bv0;
        *(uint4*)&Bs[(bn + 128) * 40 + bkp] = bv1;
        __syncthreads();

        // prefetch next K-tile; latency hides under ds_read + MFMA below
        if (k0 + 32 < K) {
            a0 = *(const float4*)(A + aoff + k0 + 32);
            a1 = *(const float4*)(A + aoff + k0 + 36);
            bv0 = *(const uint4*)(Bt + boff0 + k0 + 32);
            bv1 = *(const uint4*)(Bt + boff1 + k0 + 32);
        }

        bf16x8 af[4], bfr[4];
#pragma unroll
        for (int mt = 0; mt < 4; ++mt)
            af[mt] = *(const bf16x8*)&As[(wr * 64 + mt * 16 + l) * 40 + quad * 8];
#pragma unroll
        for (int nt = 0; nt < 4; ++nt)
            bfr[nt] = *(const bf16x8*)&Bs[(wc * 64 + nt * 16 + l) * 40 + quad * 8];
#pragma unroll
        for (int mt = 0; mt < 4; ++mt)
#pragma unroll
            for (int nt = 0; nt < 4; ++nt)
                acc[mt][nt] = __builtin_amdgcn_mfma_f32_16x16x32_bf16(
                    af[mt], bfr[nt], acc[mt][nt], 0, 0, 0);
    }

    // per-lane row absmax over this wave's 64 cols
    float rmax[4][4];
#pragma unroll
    for (int mt = 0; mt < 4; ++mt)
#pragma unroll
        for (int reg = 0; reg < 4; ++reg) {
            float m = 0.f;
#pragma unroll
            for (int nt = 0; nt < 4; ++nt)
                m = fmaxf(m, fabsf(acc[mt][nt][reg]));
            rmax[mt][reg] = m;
        }
#pragma unroll
    for (int s = 1; s <= 8; s <<= 1)
#pragma unroll
        for (int mt = 0; mt < 4; ++mt)
#pragma unroll
            for (int reg = 0; reg < 4; ++reg)
                rmax[mt][reg] = fmaxf(rmax[mt][reg], __shfl_xor(rmax[mt][reg], s));
    if (l < 4) {
#pragma unroll
        for (int mt = 0; mt < 4; ++mt)
            red[wc][wr * 64 + mt * 16 + quad * 4 + l] = rmax[mt][l];
    }
    __syncthreads();
    if (tid < 128) {
        float m = fmaxf(fmaxf(red[0][tid], red[1][tid]),
                        fmaxf(red[2][tid], red[3][tid]));
        fin[tid] = m;
        int r = m0 + tid;
        if (r < M) s1[r] = m * (1.f / 127.f);
    }
    __syncthreads();

    // quantize acc -> int8 bytes
#pragma unroll
    for (int mt = 0; mt < 4; ++mt)
#pragma unroll
        for (int reg = 0; reg < 4; ++reg) {
            int rl = wr * 64 + mt * 16 + quad * 4 + reg;
            int r = m0 + rl;
            if (r >= M) continue;
            float m = fin[rl];
            float inv = m > 0.f ? 127.f / m : 0.f;
#pragma unroll
            for (int nt = 0; nt < 4; ++nt) {
                int c = wc * 64 + nt * 16 + l;
                Q[(size_t)r * 256 + c] = (char)(int)rintf(acc[mt][nt][reg] * inv);
            }
        }
}

// ---------------------------------------------------------------------------
// GEMM2+quant: Q[M,64] int8, s2[M] from A[M,256] bf16 @ Bt[64,256]^T.
// BM=128, BN=64 (full width), BK=32; 256 threads = 4 waves 2x2. Pipelined.
__global__ __launch_bounds__(256, 4)
void gemm2_q(const ushort* __restrict__ A, const ushort* __restrict__ Bt,
             char* __restrict__ Q, float* __restrict__ s2, int M) {
    constexpr int K = 256;
    __shared__ ushort As[128 * 40];
    __shared__ ushort Bs[64 * 40];
    __shared__ float red[2][128];
    __shared__ float fin[128];
    const int tid = threadIdx.x;
    const int wave = tid >> 6, lane = tid & 63;
    const int quad = lane >> 4, l = lane & 15;
    const int wr = wave >> 1, wc = wave & 1;
    const int m0 = blockIdx.x * 128;

    const int crow = tid >> 2;
    const int cpart = (tid & 3) * 8;
    const size_t aoff0 = (size_t)min(m0 + crow, M - 1) * K + cpart;
    const size_t aoff1 = (size_t)min(m0 + crow + 64, M - 1) * K + cpart;
    const size_t boff  = (size_t)crow * K + cpart;

    f32x4 acc[4][2] = {};

    uint4 a0 = *(const uint4*)(A + aoff0);
    uint4 a1 = *(const uint4*)(A + aoff1);
    uint4 b0 = *(const uint4*)(Bt + boff);

    for (int k0 = 0; k0 < K; k0 += 32) {
        __syncthreads();
        *(uint4*)&As[crow * 40 + cpart] = a0;
        *(uint4*)&As[(crow + 64) * 40 + cpart] = a1;
        *(uint4*)&Bs[crow * 40 + cpart] = b0;
        __syncthreads();

        if (k0 + 32 < K) {
            a0 = *(const uint4*)(A + aoff0 + k0 + 32);
            a1 = *(const uint4*)(A + aoff1 + k0 + 32);
            b0 = *(const uint4*)(Bt + boff + k0 + 32);
        }

        bf16x8 af[4], bfr[2];
        const ushort* ab = &As[(wr * 64 + l) * 40 + quad * 8];
#pragma unroll
        for (int mt = 0; mt < 4; ++mt)
            af[mt] = *(const bf16x8*)(ab + mt * 16 * 40);
        const ushort* bb = &Bs[(wc * 32 + l) * 40 + quad * 8];
#pragma unroll
        for (int nt = 0; nt < 2; ++nt)
            bfr[nt] = *(const bf16x8*)(bb + nt * 16 * 40);
#pragma unroll
        for (int mt = 0; mt < 4; ++mt)
#pragma unroll
            for (int nt = 0; nt < 2; ++nt)
                acc[mt][nt] = __builtin_amdgcn_mfma_f32_16x16x32_bf16(
                    af[mt], bfr[nt], acc[mt][nt], 0, 0, 0);
    }

    float rmax[4][4];
#pragma unroll
    for (int mt = 0; mt < 4; ++mt)
#pragma unroll
        for (int reg = 0; reg < 4; ++reg)
            rmax[mt][reg] = fmaxf(fabsf(acc[mt][0][reg]), fabsf(acc[mt][1][reg]));
#pragma unroll
    for (int s = 1; s <= 8; s <<= 1)
#pragma unroll
        for (int mt = 0; mt < 4; ++mt)
#pragma unroll
            for (int reg = 0; reg < 4; ++reg)
                rmax[mt][reg] = fmaxf(rmax[mt][reg], __shfl_xor(rmax[mt][reg], s));
    if (l < 4) {
#pragma unroll
        for (int mt = 0; mt < 4; ++mt)
            red[wc][wr * 64 + mt * 16 + quad * 4 + l] = rmax[mt][l];
    }
    __syncthreads();
    if (tid < 128) {
        float m = fmaxf(red[0][tid], red[1][tid]);
        fin[tid] = m;
        int r = m0 + tid;
        if (r < M) s2[r] = m * (1.f / 127.f);
    }
    __syncthreads();

#pragma unroll
    for (int mt = 0; mt < 4; ++mt)
#pragma unroll
        for (int reg = 0; reg < 4; ++reg) {
            int rl = wr * 64 + mt * 16 + quad * 4 + reg;
            int r = m0 + rl;
            if (r >= M) continue;
            float m = fin[rl];
            float inv = m > 0.f ? 127.f / m : 0.f;
#pragma unroll
            for (int nt = 0; nt < 2; ++nt) {
                int c = wc * 32 + nt * 16 + l;
                Q[(size_t)r * 64 + c] = (char)(int)rintf(acc[mt][nt][reg] * inv);
            }
        }
}

// ---------------------------------------------------------------------------
// SpMM layer1: H = relu(sum_e vals_e*s1[col_e] * Q1[col_e] + b1). Wave per
// node; lane = 4 features. Prep fused: col/vals read as int4/float4 batches,
// s1 gathered in-loop (400KB table, L2-resident). 16 gather chains in flight.
__global__ __launch_bounds__(256)
void spmm1_q(const char* __restrict__ Q, const int* __restrict__ col,
             const float* __restrict__ vals, const float* __restrict__ s,
             const int* __restrict__ rp, const float* __restrict__ bias,
             ushort* __restrict__ H, int n) {
    const int wave = threadIdx.x >> 6;
    const int lane = threadIdx.x & 63;
    const int node = blockIdx.x * 4 + wave;
    if (node >= n) return;
    const int e0 = rp[node], e1 = rp[node + 1];
    const int lb = lane * 4;
    float a0 = 0.f, a1 = 0.f, a2 = 0.f, a3 = 0.f;
    int e = e0;
    // peel to 4-edge alignment so int4/float4 batch loads are 16B-aligned
    int ehead = min(e1, (e0 + 3) & ~3);
    for (; e < ehead; ++e) {
        int c = col[e];
        float w = vals[e] * s[c];
        char4 q = *(const char4*)(Q + ((size_t)(uint)c << 8) + lb);
        a0 += w * (float)q.x;
        a1 += w * (float)q.y;
        a2 += w * (float)q.z;
        a3 += w * (float)q.w;
    }
    for (; e + 15 < e1; e += 16) {
        int4 c0 = *(const int4*)(col + e);
        int4 c1 = *(const int4*)(col + e + 4);
        int4 c2 = *(const int4*)(col + e + 8);
        int4 c3 = *(const int4*)(col + e + 12);
        float4 v0 = *(const float4*)(vals + e);
        float4 v1 = *(const float4*)(vals + e + 4);
        float4 v2 = *(const float4*)(vals + e + 8);
        float4 v3 = *(const float4*)(vals + e + 12);
        const int cc[16] = {c0.x, c0.y, c0.z, c0.w, c1.x, c1.y, c1.z, c1.w,
                            c2.x, c2.y, c2.z, c2.w, c3.x, c3.y, c3.z, c3.w};
        const float vv[16] = {v0.x, v0.y, v0.z, v0.w, v1.x, v1.y, v1.z, v1.w,
                              v2.x, v2.y, v2.z, v2.w, v3.x, v3.y, v3.z, v3.w};
        char4 q[16];
        float w[16];
#pragma unroll
        for (int u = 0; u < 16; ++u)
            q[u] = *(const char4*)(Q + ((size_t)(uint)cc[u] << 8) + lb);
#pragma unroll
        for (int u = 0; u < 16; ++u)
            w[u] = vv[u] * s[cc[u]];
#pragma unroll
        for (int u = 0; u < 16; ++u) {
            a0 += w[u] * (float)q[u].x;
            a1 += w[u] * (float)q[u].y;
            a2 += w[u] * (float)q[u].z;
            a3 += w[u] * (float)q[u].w;
        }
    }
    for (; e + 3 < e1; e += 4) {
        int4 c0 = *(const int4*)(col + e);
        float4 v0 = *(const float4*)(vals + e);
        const int cc[4] = {c0.x, c0.y, c0.z, c0.w};
        const float vv[4] = {v0.x, v0.y, v0.z, v0.w};
        char4 q[4];
        float w[4];
#pragma unroll
        for (int u = 0; u < 4; ++u)
            q[u] = *(const char4*)(Q + ((size_t)(uint)cc[u] << 8) + lb);
#pragma unroll
        for (int u = 0; u < 4; ++u)
            w[u] = vv[u] * s[cc[u]];
#pragma unroll
        for (int u = 0; u < 4; ++u) {
            a0 += w[u] * (float)q[u].x;
            a1 += w[u] * (float)q[u].y;
            a2 += w[u] * (float)q[u].z;
            a3 += w[u] * (float)q[u].w;
        }
    }
    for (; e < e1; ++e) {
        int c = col[e];
        float w = vals[e] * s[c];
        char4 q = *(const char4*)(Q + ((size_t)(uint)c << 8) + lb);
        a0 += w * (float)q.x;
        a1 += w * (float)q.y;
        a2 += w * (float)q.z;
        a3 += w * (float)q.w;
    }
    float4 b = *(const float4*)(bias + lb);
    ushort4 r;
    r.x = f2b(fmaxf(a0 + b.x, 0.f));
    r.y = f2b(fmaxf(a1 + b.y, 0.f));
    r.z = f2b(fmaxf(a2 + b.z, 0.f));
    r.w = f2b(fmaxf(a3 + b.w, 0.f));
    *(ushort4*)(H + (size_t)node * 256 + lb) = r;
}

// ---------------------------------------------------------------------------
// SpMM layer2: out = sum_e vals_e*s2[col_e] * Q2[col_e] + b2. Wave per node;
// lane = feature (1B gather/edge). Prep fused, 16-edge unroll.
__global__ __launch_bounds__(256)
void spmm2_q(const char* __restrict__ Q, const int* __restrict__ col,
             const float* __restrict__ vals, const float* __restrict__ s,
             const int* __restrict__ rp, const float* __restrict__ bias,
             float* __restrict__ O, int n) {
    const int wave = threadIdx.x >> 6;
    const int lane = threadIdx.x & 63;
    const int node = blockIdx.x * 4 + wave;
    if (node >= n) return;
    const int e0 = rp[node], e1 = rp[node + 1];
    float acc = 0.f;
    int e = e0;
    int ehead = min(e1, (e0 + 3) & ~3);
    for (; e < ehead; ++e) {
        int c = col[e];
        float w = vals[e] * s[c];
        acc += w * (float)Q[((size_t)(uint)c << 6) + lane];
    }
    for (; e + 15 < e1; e += 16) {
        int4 c0 = *(const int4*)(col + e);
        int4 c1 = *(const int4*)(col + e + 4);
        int4 c2 = *(const int4*)(col + e + 8);
        int4 c3 = *(const int4*)(col + e + 12);
        float4 v0 = *(const float4*)(vals + e);
        float4 v1 = *(const float4*)(vals + e + 4);
        float4 v2 = *(const float4*)(vals + e + 8);
        float4 v3 = *(const float4*)(vals + e + 12);
        const int cc[16] = {c0.x, c0.y, c0.z, c0.w, c1.x, c1.y, c1.z, c1.w,
                            c2.x, c2.y, c2.z, c2.w, c3.x, c3.y, c3.z, c3.w};
        const float vv[16] = {v0.x, v0.y, v0.z, v0.w, v1.x, v1.y, v1.z, v1.w,
                              v2.x, v2.y, v2.z, v2.w, v3.x, v3.y, v3.z, v3.w};
        char qb[16];
        float w[16];
#pragma unroll
        for (int u = 0; u < 16; ++u)
            qb[u] = Q[((size_t)(uint)cc[u] << 6) + lane];
#pragma unroll
        for (int u = 0; u < 16; ++u)
            w[u] = vv[u] * s[cc[u]];
#pragma unroll
        for (int u = 0; u < 16; ++u)
            acc += w[u] * (float)qb[u];
    }
    for (; e + 3 < e1; e += 4) {
        int4 c0 = *(const int4*)(col + e);
        float4 v0 = *(const float4*)(vals + e);
        const int cc[4] = {c0.x, c0.y, c0.z, c0.w};
        const float vv[4] = {v0.x, v0.y, v0.z, v0.w};
        char qb[4];
        float w[4];
#pragma unroll
        for (int u = 0; u < 4; ++u)
            qb[u] = Q[((size_t)(uint)cc[u] << 6) + lane];
#pragma unroll
        for (int u = 0; u < 4; ++u)
            w[u] = vv[u] * s[cc[u]];
#pragma unroll
        for (int u = 0; u < 4; ++u)
            acc += w[u] * (float)qb[u];
    }
    for (; e < e1; ++e) {
        int c = col[e];
        float w = vals[e] * s[c];
        acc += w * (float)Q[((size_t)(uint)c << 6) + lane];
    }
    O[(size_t)node * 64 + lane] = acc + bias[lane];
}

// ---------------------------------------------------------------------------
static inline size_t alignup(size_t x) { return (x + 255) & ~(size_t)255; }

extern "C" void kernel_launch(void* const* d_in, const int* in_sizes, int n_in,
                              void* d_out, int out_size, void* d_ws, size_t ws_size,
                              hipStream_t stream) {
    const float* X  = (const float*)d_in[0];
    const float* ev = (const float*)d_in[1];
    const float* W1 = (const float*)d_in[2];
    const float* b1 = (const float*)d_in[3];
    const float* W2 = (const float*)d_in[4];
    const float* b2 = (const float*)d_in[5];
    const int*  row = (const int*)d_in[6];
    const int*  col = (const int*)d_in[7];
    float* out = (float*)d_out;

    const int n = in_sizes[0] / IN_SIZE;   // 100000
    const int E = in_sizes[1];             // 3200000

    char* p = (char*)d_ws;
    ushort* H    = (ushort*)p; p += alignup((size_t)n * HID * 2);
    char*   Q1   = (char*)p;   p += alignup((size_t)n * HID);
    float*  s1   = (float*)p;  p += alignup((size_t)n * 4);
    char*   Q2   = (char*)p;   p += alignup((size_t)n * OUTF);
    float*  s2   = (float*)p;  p += alignup((size_t)n * 4);
    ushort* W1T  = (ushort*)p; p += alignup((size_t)IN_SIZE * HID * 2);
    ushort* W2T  = (ushort*)p; p += alignup((size_t)HID * OUTF * 2);
    int*    rp   = (int*)p;    p += alignup((size_t)(n + 1) * 4);

    const int rpB = (n + 1 + 255) / 256;
    setup_kernel<<<rpB + 256 + 64, 256, 0, stream>>>(row, rp, W1, W1T, W2, W2T,
                                                     n, E, rpB);

    // Q1,s1 = int8rowquant(bf16(X) @ W1)
    gemm1_q<<<(n + 127) / 128, 512, 0, stream>>>(X, W1T, Q1, s1, n);

    // H = relu(A @ deq(Q1) + b1)   (prep fused)
    spmm1_q<<<(n + 3) / 4, 256, 0, stream>>>(Q1, col, ev, s1, rp, b1, H, n);

    // Q2,s2 = int8rowquant(H @ W2)
    gemm2_q<<<(n + 127) / 128, 256, 0, stream>>>(H, W2T, Q2, s2, n);

    // out = A @ deq(Q2) + b2   (prep fused)
    spmm2_q<<<(n + 3) / 4, 256, 0, stream>>>(Q2, col, ev, s2, rp, b2, out, n);
}

// Round 2
// 454.783 us; speedup vs baseline: 1.0926x; 1.0926x over previous
//
#include <hip/hip_runtime.h>

// GCN: out = A*(relu(A*(X*W1)+b1)*W2)+b2, A sparse COO, sorted row[].
// N=100000, E=3200000, IN=256, HID=256, OUT=64.
// Pipeline (7 launches, wide-gather spmm, biased-uint8 Q):
//   setup: rowptr + W1T + W2T
//   gemm1: Q1,s1 = u8rowquant(bf16(X)@W1)     (512thr, BM=128 BN=256)
//   prep1: ew = {col<<8, vals*s1[col]}
//   spmm1: H = relu(A@deq(Q1)+b1) -> bf16     (4 edges/gather, 16B/lane)
//   gemm2: Q2,s2 = u8rowquant(H@W2)           (256thr, BM=128 BN=64)
//   prep2: ew = {col<<6, vals*s2[col]}
//   spmm2: out = A@deq(Q2)+b2 -> fp32         (8 edges/gather, 8B/lane)
// Q stored biased (+128, uint8): unpack = v_cvt_f32_ubyteN; exact fixup
// via acc - 128*sumw at the node end.

constexpr int IN_SIZE = 256;
constexpr int HID = 256;
constexpr int OUTF = 64;

typedef __bf16 bf16x8 __attribute__((ext_vector_type(8)));
typedef float f32x4 __attribute__((ext_vector_type(4)));

__device__ __forceinline__ ushort f2b(float f) {
    uint u = __float_as_uint(f);
    uint r = (u + 0x7fffu + ((u >> 16) & 1u)) >> 16;   // RNE
    return (ushort)r;
}

__device__ __forceinline__ void fma4(float* a, uint word, float w) {
    a[0] += w * (float)(word & 0xffu);
    a[1] += w * (float)((word >> 8) & 0xffu);
    a[2] += w * (float)((word >> 16) & 0xffu);
    a[3] += w * (float)(word >> 24);
}

// ---------------------------------------------------------------------------
// setup: blocks [0,rpB): row_ptr; [rpB,rpB+256): W1T; [rpB+256,rpB+320): W2T
__global__ void setup_kernel(const int* __restrict__ row, int* __restrict__ rp,
                             const float* __restrict__ W1, ushort* __restrict__ W1T,
                             const float* __restrict__ W2, ushort* __restrict__ W2T,
                             int n, int E, int rpB) {
    int b = blockIdx.x;
    if (b < rpB) {
        int i = b * 256 + threadIdx.x;
        if (i > n) return;
        int lo = 0, hi = E;
        while (lo < hi) {
            int mid = (lo + hi) >> 1;
            if (row[mid] < i) lo = mid + 1; else hi = mid;
        }
        rp[i] = lo;
    } else if (b < rpB + 256) {
        int nn = b - rpB;
        int k = threadIdx.x;
        W1T[(size_t)nn * 256 + k] = f2b(W1[(size_t)k * 256 + nn]);
    } else {
        int nn = b - rpB - 256;
        int k = threadIdx.x;
        W2T[(size_t)nn * 256 + k] = f2b(W2[(size_t)k * 64 + nn]);
    }
}

// prep: ew[e] = {col[e]<<shift (byte offset into Q), vals[e]*s[col[e]]}
__global__ void prep_edges(const float* __restrict__ vals, const int* __restrict__ col,
                           const float* __restrict__ s, int2* __restrict__ ew,
                           int E, int shift) {
    int e = blockIdx.x * 256 + threadIdx.x;
    if (e >= E) return;
    int c = col[e];
    ew[e] = make_int2(c << shift, __float_as_int(vals[e] * s[c]));
}

// ---------------------------------------------------------------------------
// GEMM1+quant: Q[M,256] biased-u8, s1[M] from bf16(X_f32[M,256]) @ Bt^T.
// BM=128, BN=256, BK=32. 512 threads = 8 waves 2x4; wave tile 64x64.
// K-loop software-pipelined: next tile's globals issue after the publish
// barrier, latency hides under ds_read+MFMA.
__global__ __launch_bounds__(512)
void gemm1_q(const float* __restrict__ A, const ushort* __restrict__ Bt,
             unsigned char* __restrict__ Q, float* __restrict__ s1, int M) {
    constexpr int K = 256;
    __shared__ ushort As[128 * 40];
    __shared__ ushort Bs[256 * 40];
    __shared__ float red[4][128];
    __shared__ float fin[128];
    const int tid = threadIdx.x;
    const int wave = tid >> 6, lane = tid & 63;
    const int quad = lane >> 4, l = lane & 15;
    const int wr = wave >> 2, wc = wave & 3;     // 2 x 4 wave grid
    const int m0 = blockIdx.x * 128;

    const int ar = tid >> 2;
    const int ak = (tid & 3) * 8;
    const size_t aoff = (size_t)min(m0 + ar, M - 1) * K + ak;
    const int bn = tid >> 2;
    const int bkp = (tid & 3) * 8;
    const size_t boff0 = (size_t)bn * K + bkp;
    const size_t boff1 = (size_t)(bn + 128) * K + bkp;

    f32x4 acc[4][4] = {};

    float4 a0 = *(const float4*)(A + aoff);
    float4 a1 = *(const float4*)(A + aoff + 4);
    uint4 bv0 = *(const uint4*)(Bt + boff0);
    uint4 bv1 = *(const uint4*)(Bt + boff1);

    for (int k0 = 0; k0 < K; k0 += 32) {
        uint4 pa;
        pa.x = (uint)f2b(a0.x) | ((uint)f2b(a0.y) << 16);
        pa.y = (uint)f2b(a0.z) | ((uint)f2b(a0.w) << 16);
        pa.z = (uint)f2b(a1.x) | ((uint)f2b(a1.y) << 16);
        pa.w = (uint)f2b(a1.z) | ((uint)f2b(a1.w) << 16);
        __syncthreads();
        *(uint4*)&As[ar * 40 + ak] = pa;
        *(uint4*)&Bs[bn * 40 + bkp] = bv0;
        *(uint4*)&Bs[(bn + 128) * 40 + bkp] = bv1;
        __syncthreads();

        if (k0 + 32 < K) {
            a0 = *(const float4*)(A + aoff + k0 + 32);
            a1 = *(const float4*)(A + aoff + k0 + 36);
            bv0 = *(const uint4*)(Bt + boff0 + k0 + 32);
            bv1 = *(const uint4*)(Bt + boff1 + k0 + 32);
        }

        bf16x8 af[4], bfr[4];
#pragma unroll
        for (int mt = 0; mt < 4; ++mt)
            af[mt] = *(const bf16x8*)&As[(wr * 64 + mt * 16 + l) * 40 + quad * 8];
#pragma unroll
        for (int nt = 0; nt < 4; ++nt)
            bfr[nt] = *(const bf16x8*)&Bs[(wc * 64 + nt * 16 + l) * 40 + quad * 8];
#pragma unroll
        for (int mt = 0; mt < 4; ++mt)
#pragma unroll
            for (int nt = 0; nt < 4; ++nt)
                acc[mt][nt] = __builtin_amdgcn_mfma_f32_16x16x32_bf16(
                    af[mt], bfr[nt], acc[mt][nt], 0, 0, 0);
    }

    // per-lane row absmax over this wave's 64 cols
    float rmax[4][4];
#pragma unroll
    for (int mt = 0; mt < 4; ++mt)
#pragma unroll
        for (int reg = 0; reg < 4; ++reg) {
            float m = 0.f;
#pragma unroll
            for (int nt = 0; nt < 4; ++nt)
                m = fmaxf(m, fabsf(acc[mt][nt][reg]));
            rmax[mt][reg] = m;
        }
#pragma unroll
    for (int s = 1; s <= 8; s <<= 1)
#pragma unroll
        for (int mt = 0; mt < 4; ++mt)
#pragma unroll
            for (int reg = 0; reg < 4; ++reg)
                rmax[mt][reg] = fmaxf(rmax[mt][reg], __shfl_xor(rmax[mt][reg], s));
    if (l < 4) {
#pragma unroll
        for (int mt = 0; mt < 4; ++mt)
            red[wc][wr * 64 + mt * 16 + quad * 4 + l] = rmax[mt][l];
    }
    __syncthreads();
    if (tid < 128) {
        float m = fmaxf(fmaxf(red[0][tid], red[1][tid]),
                        fmaxf(red[2][tid], red[3][tid]));
        fin[tid] = m;
        int r = m0 + tid;
        if (r < M) s1[r] = m * (1.f / 127.f);
    }
    __syncthreads();

    // quantize acc -> biased uint8
#pragma unroll
    for (int mt = 0; mt < 4; ++mt)
#pragma unroll
        for (int reg = 0; reg < 4; ++reg) {
            int rl = wr * 64 + mt * 16 + quad * 4 + reg;
            int r = m0 + rl;
            if (r >= M) continue;
            float m = fin[rl];
            float inv = m > 0.f ? 127.f / m : 0.f;
#pragma unroll
            for (int nt = 0; nt < 4; ++nt) {
                int c = wc * 64 + nt * 16 + l;
                Q[(size_t)r * 256 + c] =
                    (unsigned char)((int)rintf(acc[mt][nt][reg] * inv) + 128);
            }
        }
}

// ---------------------------------------------------------------------------
// GEMM2+quant: Q[M,64] biased-u8, s2[M] from A[M,256] bf16 @ Bt[64,256]^T.
// BM=128, BN=64, BK=32; 256 threads = 4 waves 2x2. Pipelined.
__global__ __launch_bounds__(256, 4)
void gemm2_q(const ushort* __restrict__ A, const ushort* __restrict__ Bt,
             unsigned char* __restrict__ Q, float* __restrict__ s2, int M) {
    constexpr int K = 256;
    __shared__ ushort As[128 * 40];
    __shared__ ushort Bs[64 * 40];
    __shared__ float red[2][128];
    __shared__ float fin[128];
    const int tid = threadIdx.x;
    const int wave = tid >> 6, lane = tid & 63;
    const int quad = lane >> 4, l = lane & 15;
    const int wr = wave >> 1, wc = wave & 1;
    const int m0 = blockIdx.x * 128;

    const int crow = tid >> 2;
    const int cpart = (tid & 3) * 8;
    const size_t aoff0 = (size_t)min(m0 + crow, M - 1) * K + cpart;
    const size_t aoff1 = (size_t)min(m0 + crow + 64, M - 1) * K + cpart;
    const size_t boff  = (size_t)crow * K + cpart;

    f32x4 acc[4][2] = {};

    uint4 a0 = *(const uint4*)(A + aoff0);
    uint4 a1 = *(const uint4*)(A + aoff1);
    uint4 b0 = *(const uint4*)(Bt + boff);

    for (int k0 = 0; k0 < K; k0 += 32) {
        __syncthreads();
        *(uint4*)&As[crow * 40 + cpart] = a0;
        *(uint4*)&As[(crow + 64) * 40 + cpart] = a1;
        *(uint4*)&Bs[crow * 40 + cpart] = b0;
        __syncthreads();

        if (k0 + 32 < K) {
            a0 = *(const uint4*)(A + aoff0 + k0 + 32);
            a1 = *(const uint4*)(A + aoff1 + k0 + 32);
            b0 = *(const uint4*)(Bt + boff + k0 + 32);
        }

        bf16x8 af[4], bfr[2];
        const ushort* ab = &As[(wr * 64 + l) * 40 + quad * 8];
#pragma unroll
        for (int mt = 0; mt < 4; ++mt)
            af[mt] = *(const bf16x8*)(ab + mt * 16 * 40);
        const ushort* bb = &Bs[(wc * 32 + l) * 40 + quad * 8];
#pragma unroll
        for (int nt = 0; nt < 2; ++nt)
            bfr[nt] = *(const bf16x8*)(bb + nt * 16 * 40);
#pragma unroll
        for (int mt = 0; mt < 4; ++mt)
#pragma unroll
            for (int nt = 0; nt < 2; ++nt)
                acc[mt][nt] = __builtin_amdgcn_mfma_f32_16x16x32_bf16(
                    af[mt], bfr[nt], acc[mt][nt], 0, 0, 0);
    }

    float rmax[4][4];
#pragma unroll
    for (int mt = 0; mt < 4; ++mt)
#pragma unroll
        for (int reg = 0; reg < 4; ++reg)
            rmax[mt][reg] = fmaxf(fabsf(acc[mt][0][reg]), fabsf(acc[mt][1][reg]));
#pragma unroll
    for (int s = 1; s <= 8; s <<= 1)
#pragma unroll
        for (int mt = 0; mt < 4; ++mt)
#pragma unroll
            for (int reg = 0; reg < 4; ++reg)
                rmax[mt][reg] = fmaxf(rmax[mt][reg], __shfl_xor(rmax[mt][reg], s));
    if (l < 4) {
#pragma unroll
        for (int mt = 0; mt < 4; ++mt)
            red[wc][wr * 64 + mt * 16 + quad * 4 + l] = rmax[mt][l];
    }
    __syncthreads();
    if (tid < 128) {
        float m = fmaxf(red[0][tid], red[1][tid]);
        fin[tid] = m;
        int r = m0 + tid;
        if (r < M) s2[r] = m * (1.f / 127.f);
    }
    __syncthreads();

#pragma unroll
    for (int mt = 0; mt < 4; ++mt)
#pragma unroll
        for (int reg = 0; reg < 4; ++reg) {
            int rl = wr * 64 + mt * 16 + quad * 4 + reg;
            int r = m0 + rl;
            if (r >= M) continue;
            float m = fin[rl];
            float inv = m > 0.f ? 127.f / m : 0.f;
#pragma unroll
            for (int nt = 0; nt < 2; ++nt) {
                int c = wc * 32 + nt * 16 + l;
                Q[(size_t)r * 64 + c] =
                    (unsigned char)((int)rintf(acc[mt][nt][reg] * inv) + 128);
            }
        }
}

// ---------------------------------------------------------------------------
// SpMM layer1: H = relu(A@deq(Q1)+b1). Wave per node. 16B/lane gather:
// lane = {edge slot g=lane>>4, feature block fl=lane&15}; one uint4 gather
// covers 4 edges x 256B rows per instruction (1KB payload). Per-lane acc =
// 16 features; butterfly (s=16,32) reduces the 4 edge slots at node end.
// Biased-u8 fixup: result = acc - 128*sumw + bias.
__global__ __launch_bounds__(256)
void spmm1_q(const unsigned char* __restrict__ Q, const int2* __restrict__ ew,
             const int* __restrict__ rp, const float* __restrict__ bias,
             ushort* __restrict__ H, int n) {
    const int wave = threadIdx.x >> 6;
    const int lane = threadIdx.x & 63;
    const int node = blockIdx.x * 4 + wave;
    if (node >= n) return;
    const int e0 = rp[node], e1 = rp[node + 1];
    const int g = lane >> 4;            // edge slot 0..3
    const int fb = (lane & 15) * 16;    // byte offset of 16 features

    float acc[16] = {};
    float sumw = 0.f;
    int e = e0;
    // main: 16 edges per iter, unmasked
    for (; e + 16 <= e1; e += 16) {
#pragma unroll
        for (int u = 0; u < 4; ++u) {
            int2 m = ew[e + u * 4 + g];
            float w = __int_as_float(m.y);
            uint4 qv = *(const uint4*)(Q + (size_t)(uint)m.x + fb);
            sumw += w;
            fma4(&acc[0], qv.x, w);
            fma4(&acc[4], qv.y, w);
            fma4(&acc[8], qv.z, w);
            fma4(&acc[12], qv.w, w);
        }
    }
    // tail: 4 edges per iter, masked (ewb padded by 16 entries)
    for (; e < e1; e += 4) {
        int idx = e + g;
        int2 m = ew[idx];
        bool ok = idx < e1;
        uint off = ok ? (uint)m.x : 0u;
        float w = ok ? __int_as_float(m.y) : 0.f;
        uint4 qv = *(const uint4*)(Q + (size_t)off + fb);
        sumw += w;
        fma4(&acc[0], qv.x, w);
        fma4(&acc[4], qv.y, w);
        fma4(&acc[8], qv.z, w);
        fma4(&acc[12], qv.w, w);
    }

    // reduce edge slots: butterfly across lane groups of 16
#pragma unroll
    for (int s = 16; s <= 32; s <<= 1) {
#pragma unroll
        for (int j = 0; j < 16; ++j)
            acc[j] += __shfl_xor(acc[j], s);
        sumw += __shfl_xor(sumw, s);
    }

    if (g == 0) {
        const int f0 = (lane & 15) * 16;
        float4 b0 = *(const float4*)(bias + f0);
        float4 b1 = *(const float4*)(bias + f0 + 4);
        float4 b2 = *(const float4*)(bias + f0 + 8);
        float4 b3 = *(const float4*)(bias + f0 + 12);
        float bb[16] = {b0.x, b0.y, b0.z, b0.w, b1.x, b1.y, b1.z, b1.w,
                        b2.x, b2.y, b2.z, b2.w, b3.x, b3.y, b3.z, b3.w};
        float fix = -128.f * sumw;
        ushort r[16];
#pragma unroll
        for (int j = 0; j < 16; ++j)
            r[j] = f2b(fmaxf(acc[j] + fix + bb[j], 0.f));
        uint4 w0, w1;
        w0.x = (uint)r[0] | ((uint)r[1] << 16);
        w0.y = (uint)r[2] | ((uint)r[3] << 16);
        w0.z = (uint)r[4] | ((uint)r[5] << 16);
        w0.w = (uint)r[6] | ((uint)r[7] << 16);
        w1.x = (uint)r[8] | ((uint)r[9] << 16);
        w1.y = (uint)r[10] | ((uint)r[11] << 16);
        w1.z = (uint)r[12] | ((uint)r[13] << 16);
        w1.w = (uint)r[14] | ((uint)r[15] << 16);
        *(uint4*)(H + (size_t)node * 256 + f0) = w0;
        *(uint4*)(H + (size_t)node * 256 + f0 + 8) = w1;
    }
}

// ---------------------------------------------------------------------------
// SpMM layer2: out = A@deq(Q2)+b2. Wave per node. 8B/lane gather: lane =
// {edge slot g=lane>>3, feature block fl=lane&7}; one uint2 gather covers
// 8 edges x 64B rows (512B payload). Butterfly s=8,16,32.
__global__ __launch_bounds__(256)
void spmm2_q(const unsigned char* __restrict__ Q, const int2* __restrict__ ew,
             const int* __restrict__ rp, const float* __restrict__ bias,
             float* __restrict__ O, int n) {
    const int wave = threadIdx.x >> 6;
    const int lane = threadIdx.x & 63;
    const int node = blockIdx.x * 4 + wave;
    if (node >= n) return;
    const int e0 = rp[node], e1 = rp[node + 1];
    const int g = lane >> 3;           // edge slot 0..7
    const int fb = (lane & 7) * 8;     // byte offset of 8 features

    float acc[8] = {};
    float sumw = 0.f;
    int e = e0;
    // main: 16 edges per iter, unmasked
    for (; e + 16 <= e1; e += 16) {
#pragma unroll
        for (int u = 0; u < 2; ++u) {
            int2 m = ew[e + u * 8 + g];
            float w = __int_as_float(m.y);
            uint2 qv = *(const uint2*)(Q + (size_t)(uint)m.x + fb);
            sumw += w;
            fma4(&acc[0], qv.x, w);
            fma4(&acc[4], qv.y, w);
        }
    }
    // tail: 8 edges per iter, masked
    for (; e < e1; e += 8) {
        int idx = e + g;
        int2 m = ew[idx];
        bool ok = idx < e1;
        uint off = ok ? (uint)m.x : 0u;
        float w = ok ? __int_as_float(m.y) : 0.f;
        uint2 qv = *(const uint2*)(Q + (size_t)off + fb);
        sumw += w;
        fma4(&acc[0], qv.x, w);
        fma4(&acc[4], qv.y, w);
    }

#pragma unroll
    for (int s = 8; s <= 32; s <<= 1) {
#pragma unroll
        for (int j = 0; j < 8; ++j)
            acc[j] += __shfl_xor(acc[j], s);
        sumw += __shfl_xor(sumw, s);
    }

    if (g == 0) {
        const int f0 = (lane & 7) * 8;
        float4 b0 = *(const float4*)(bias + f0);
        float4 b1 = *(const float4*)(bias + f0 + 4);
        float fix = -128.f * sumw;
        float4 o0, o1;
        o0.x = acc[0] + fix + b0.x;
        o0.y = acc[1] + fix + b0.y;
        o0.z = acc[2] + fix + b0.z;
        o0.w = acc[3] + fix + b0.w;
        o1.x = acc[4] + fix + b1.x;
        o1.y = acc[5] + fix + b1.y;
        o1.z = acc[6] + fix + b1.z;
        o1.w = acc[7] + fix + b1.w;
        *(float4*)(O + (size_t)node * 64 + f0) = o0;
        *(float4*)(O + (size_t)node * 64 + f0 + 4) = o1;
    }
}

// ---------------------------------------------------------------------------
static inline size_t alignup(size_t x) { return (x + 255) & ~(size_t)255; }

extern "C" void kernel_launch(void* const* d_in, const int* in_sizes, int n_in,
                              void* d_out, int out_size, void* d_ws, size_t ws_size,
                              hipStream_t stream) {
    const float* X  = (const float*)d_in[0];
    const float* ev = (const float*)d_in[1];
    const float* W1 = (const float*)d_in[2];
    const float* b1 = (const float*)d_in[3];
    const float* W2 = (const float*)d_in[4];
    const float* b2 = (const float*)d_in[5];
    const int*  row = (const int*)d_in[6];
    const int*  col = (const int*)d_in[7];
    float* out = (float*)d_out;

    const int n = in_sizes[0] / IN_SIZE;   // 100000
    const int E = in_sizes[1];             // 3200000

    char* p = (char*)d_ws;
    ushort* H    = (ushort*)p; p += alignup((size_t)n * HID * 2);
    unsigned char* Q1 = (unsigned char*)p; p += alignup((size_t)n * HID);
    float*  s1   = (float*)p;  p += alignup((size_t)n * 4);
    unsigned char* Q2 = (unsigned char*)p; p += alignup((size_t)n * OUTF);
    float*  s2   = (float*)p;  p += alignup((size_t)n * 4);
    ushort* W1T  = (ushort*)p; p += alignup((size_t)IN_SIZE * HID * 2);
    ushort* W2T  = (ushort*)p; p += alignup((size_t)HID * OUTF * 2);
    int*    rp   = (int*)p;    p += alignup((size_t)(n + 1) * 4);
    int2*   ewb  = (int2*)p;   p += alignup((size_t)(E + 16) * 8);  // +16 pad for masked tail reads

    const int rpB = (n + 1 + 255) / 256;
    setup_kernel<<<rpB + 256 + 64, 256, 0, stream>>>(row, rp, W1, W1T, W2, W2T,
                                                     n, E, rpB);

    // Q1,s1 = u8rowquant(bf16(X) @ W1)
    gemm1_q<<<(n + 127) / 128, 512, 0, stream>>>(X, W1T, Q1, s1, n);

    // ew = {col<<8, vals*s1[col]}
    prep_edges<<<(E + 255) / 256, 256, 0, stream>>>(ev, col, s1, ewb, E, 8);

    // H = relu(A @ deq(Q1) + b1)
    spmm1_q<<<(n + 3) / 4, 256, 0, stream>>>(Q1, ewb, rp, b1, H, n);

    // Q2,s2 = u8rowquant(H @ W2)
    gemm2_q<<<(n + 127) / 128, 256, 0, stream>>>(H, W2T, Q2, s2, n);

    // ew = {col<<6, vals*s2[col]}
    prep_edges<<<(E + 255) / 256, 256, 0, stream>>>(ev, col, s2, ewb, E, 6);

    // out = A @ deq(Q2) + b2
    spmm2_q<<<(n + 3) / 4, 256, 0, stream>>>(Q2, ewb, rp, b2, out, n);
}